// Round 2
// baseline (1290.405 us; speedup 1.0000x reference)
//
#include <hip/hip_runtime.h>
#include <cstdint>

#define N_EDGES 12288
#define ROWLEN  2432      // 19*128 floats per edge
#define CAP     2048      // per-system bucket capacity (buckets avg 768)

typedef __bf16 bf16;
typedef __bf16 bf16x8 __attribute__((ext_vector_type(8)));
typedef float  f32x4  __attribute__((ext_vector_type(4)));

#define ELEMS0 (640*640)
#define ELEMS1 (1024*1024)
#define ELEMS2 (768*768)

// ws byte offsets (xb buffer removed - A is cast f32->bf16 in-kernel now)
#define WS_IDX_OFF   1024
#define WS_BIAS_OFF  (WS_IDX_OFF + 16*CAP*4)                 // 132096
#define WS_W_OFF     (WS_BIAS_OFF + 16*640*4)                // 173056
#define WZ_ELEMS     ((size_t)16*(ELEMS0+ELEMS1+ELEMS2))     // 32.77M bf16
#define WS_NEED      (WS_W_OFF + WZ_ELEMS*2)                 // ~65.7 MB

// After the SO(2) "hat" fold every branch is a square GEMM with K == N.
template<int B> struct Cfg;
template<> struct Cfg<0> { static constexpr int K=640,  KS=640, XOFF=0,    NT=5;
                           static constexpr size_t WOFF=0; };
template<> struct Cfg<1> { static constexpr int K=1024, KS=512, XOFF=640,  NT=8;
                           static constexpr size_t WOFF=(size_t)16*ELEMS0; };
template<> struct Cfg<2> { static constexpr int K=768,  KS=384, XOFF=1664, NT=6;
                           static constexpr size_t WOFF=(size_t)16*ELEMS0+(size_t)16*ELEMS1; };

__device__ __forceinline__ void async_copy16(const void* g, void* l) {
  // global -> LDS direct copy, 16B/lane; LDS dest = wave-uniform base + lane*16.
  auto gp = reinterpret_cast<const __attribute__((address_space(1))) unsigned int*>(
      reinterpret_cast<uintptr_t>(g));
  auto lp = reinterpret_cast<__attribute__((address_space(3))) unsigned int*>(
      (unsigned int)reinterpret_cast<uintptr_t>(l));
  __builtin_amdgcn_global_load_lds(gp, lp, 16, 0, 0);
}

// ---------------- bucketing: LDS histogram, 16 global atomics per block ------
__global__ void bucket_kernel(const int* __restrict__ eb, int* __restrict__ counts,
                              int* __restrict__ idxb) {
  __shared__ int hcnt[16], hbase[16];
  int tid = threadIdx.x;
  int t = blockIdx.x * 256 + tid;
  if (tid < 16) hcnt[tid] = 0;
  __syncthreads();
  int s = -1, lp = 0;
  if (t < N_EDGES) { s = eb[t]; lp = atomicAdd(&hcnt[s], 1); }
  __syncthreads();
  if (tid < 16) hbase[tid] = atomicAdd(counts + tid, hcnt[tid]);
  __syncthreads();
  if (s >= 0) { int p = hbase[s] + lp; if (p < CAP) idxb[s * CAP + p] = t; }
}

// ---------------- mixed bias ----------------
__global__ void bias_kernel(const float* __restrict__ ce, const float* __restrict__ b0,
                            float* __restrict__ bias) {
  int t = blockIdx.x * 256 + threadIdx.x;   // 0..10239
  int s = t / 640, c = t - s * 640;
  float a = 0.f;
#pragma unroll
  for (int e = 0; e < 8; ++e) a += ce[s * 8 + e] * b0[e * 640 + c];
  bias[t] = a;
}

// ---------------- weight mixing + hat fold + swizzle + bf16 cast ----------------
// dst layout per (branch, system): [kblk][chunk128][kgrp:4][n:128][k8:8] bf16.
template<int B>
__device__ __forceinline__ void mix_body(const float* __restrict__ Wsrc,
                                         const float* ce_s,
                                         unsigned short* __restrict__ Wz, int pos) {
  constexpr int N = Cfg<B>::K, KS = Cfg<B>::KS, NT = N / 128, HALF = N / 2;
  constexpr int SRC_STRIDE = KS * N;
  constexpr size_t DST_STRIDE = (size_t)Cfg<B>::K * N;
  int nn = pos & 127, kgrp = (pos >> 7) & 3, rest = pos >> 9;
  int nt = rest % NT, kblk = rest / NT;
  int i0 = kblk * 32 + kgrp * 8;
  int c  = nt * 128 + nn;
  int si = i0, sc = c; float sg = 1.f;
  if (B > 0 && i0 >= KS) {                      // lower half of hat: [-W2 | W1]
    si = i0 - KS;
    if (c < HALF) { sc = c + HALF; sg = -1.f; } else { sc = c - HALF; }
  }
  float w[8][8];
  const float* p0 = Wsrc + (size_t)si * N + sc;
#pragma unroll
  for (int e = 0; e < 8; ++e) {
    const float* p = p0 + (size_t)e * SRC_STRIDE;
#pragma unroll
    for (int j = 0; j < 8; ++j)
      w[e][j] = sg * __builtin_nontemporal_load(p + (size_t)j * N);  // Wsrc read once
  }
  unsigned short* db = Wz + Cfg<B>::WOFF + (size_t)pos * 8;
#pragma unroll
  for (int s = 0; s < 16; ++s) {
    float a[8] = {0, 0, 0, 0, 0, 0, 0, 0};
#pragma unroll
    for (int e = 0; e < 8; ++e) {
      float cc = ce_s[s * 8 + e];
#pragma unroll
      for (int j = 0; j < 8; ++j) a[j] += cc * w[e][j];
    }
    bf16x8 v;
#pragma unroll
    for (int j = 0; j < 8; ++j) v[j] = (bf16)a[j];
    *(bf16x8*)(db + s * DST_STRIDE) = v;
  }
}

__global__ __launch_bounds__(256) void mix_all(const float* __restrict__ W0,
                                               const float* __restrict__ W1,
                                               const float* __restrict__ W2,
                                               const float* __restrict__ ce,
                                               unsigned short* __restrict__ Wz) {
  __shared__ float ce_s[128];
  int tid = threadIdx.x;
  if (tid < 128) ce_s[tid] = ce[tid];
  __syncthreads();
  int bx = blockIdx.x;
  if (bx < 200)      mix_body<0>(W0, ce_s, Wz, bx * 256 + tid);
  else if (bx < 712) mix_body<1>(W1, ce_s, Wz, (bx - 200) * 256 + tid);
  else               mix_body<2>(W2, ce_s, Wz, (bx - 712) * 256 + tid);
}

// ---------------- grouped GEMM: 256x256 tile, 8 waves, dbuf ------------------
// A: f32 global -> reg -> cvt -> bf16 LDS (no pre-cast pass, no xb buffer).
// B: bf16 global_load_lds direct. out: PLAIN f32 stores (nt stores defeated L2
// write-merge in round 1: WRITE_SIZE 117MB -> 2.07GB, 16x inflation. Reverted.)
template<int B>
__device__ __forceinline__ void gemm_body(
    const float* __restrict__ x, const char* __restrict__ zeros,
    const unsigned short* __restrict__ Wz,
    const int* __restrict__ counts, const int* __restrict__ idxb,
    const float* __restrict__ bias, float* __restrict__ out,
    int s, int mt, int nt2, char* sm)
{
  constexpr int K = Cfg<B>::K, NT = Cfg<B>::NT, KB = K / 32, XOFF = Cfg<B>::XOFF;
  int cnt = counts[s];
  int m0 = mt * 256;
  if (m0 >= cnt) return;
  int tid = threadIdx.x;
  // LDS: A bufs 2x16KB ([kq:4][row:256] 16B chunks), B bufs 2x16KB. Total 64KB.
  char* lA0 = sm;           char* lA1 = sm + 16384;
  char* lB0 = sm + 32768;   char* lB1 = sm + 49152;
  int wv = tid >> 6, ln = tid & 63;
  int wm = wv >> 1, wn = wv & 1;          // 4m x 2n waves, each owns 64x128 output
  int kq = ln >> 4, lm = ln & 15;
  int c0 = nt2 * 2;
  // A source: two threads per row; h selects k-half [h*16, h*16+16) of the 32-k tile
  int r_a = tid >> 1, h = tid & 1;
  const char* arow; int kinc;
  { int e = (m0 + r_a < cnt) ? idxb[s * CAP + m0 + r_a] : -1;
    if (e >= 0) { arow = (const char*)(x + (size_t)e * ROWLEN + XOFF); kinc = 128; }
    else        { arow = zeros; kinc = 0; } }
  const unsigned short* wb = Wz + Cfg<B>::WOFF + (size_t)s * K * K;

  f32x4 sreg[4];                                   // staged A (16 f32)
  auto loadA = [&](int kb) {                       // issue early (T14 split)
    const char* p = arow + (size_t)kb * kinc + h * 64;
#pragma unroll
    for (int i = 0; i < 4; ++i) sreg[i] = *(const f32x4*)(p + i * 16);
  };
  auto writeA = [&](char* dst) {                   // cvt + ds_write late
#pragma unroll
    for (int c = 0; c < 2; ++c) {
      bf16x8 v;
#pragma unroll
      for (int j = 0; j < 8; ++j) v[j] = (bf16)sreg[c * 2 + (j >> 2)][j & 3];
      *(bf16x8*)(dst + ((2 * h + c) * 256 + r_a) * 16) = v;   // chunk (kq=2h+c, row)
    }
  };
  auto stageB = [&](int kb, char* dst) {
    const unsigned short* base = wb + (size_t)kb * (NT * 4096);
#pragma unroll
    for (int i = 0; i < 2; ++i) {
      int c = i * 512 + tid;                       // 1024 16B chunks per buf
      int ck = c0 + (c >> 9); if (ck > NT - 1) ck = NT - 1;   // clamp (dup, discarded)
      async_copy16(base + (size_t)ck * 4096 + (c & 511) * 8,
                   dst + (i * 512 + wv * 64) * 16);
    }
  };

  f32x4 acc[4][8];
#pragma unroll
  for (int i = 0; i < 4; ++i)
#pragma unroll
    for (int j = 0; j < 8; ++j) {
      acc[i][j][0] = 0.f; acc[i][j][1] = 0.f; acc[i][j][2] = 0.f; acc[i][j][3] = 0.f;
    }

  loadA(0); stageB(0, lB0); writeA(lA0);
#pragma unroll 1
  for (int kb = 0; kb < KB; ++kb) {
    __syncthreads();                              // drains stage(kb) issued last iter
    char* la = (kb & 1) ? lA1 : lA0;
    char* lb = (kb & 1) ? lB1 : lB0;
    if (kb + 1 < KB) {                            // issue next-tile loads first
      loadA(kb + 1);
      stageB(kb + 1, (kb & 1) ? lB0 : lB1);
    }
    bf16x8 af[4], bq[8];
#pragma unroll
    for (int mi = 0; mi < 4; ++mi)
      af[mi] = *(const bf16x8*)(la + kq * 4096 + (wm * 64 + mi * 16 + lm) * 16);
#pragma unroll
    for (int ni = 0; ni < 8; ++ni)
      bq[ni] = *(const bf16x8*)(lb + wn * 8192 + kq * 2048 + (ni * 16 + lm) * 16);
#pragma unroll
    for (int mi = 0; mi < 4; ++mi)
#pragma unroll
      for (int ni = 0; ni < 8; ++ni)
        acc[mi][ni] = __builtin_amdgcn_mfma_f32_16x16x32_bf16(af[mi], bq[ni], acc[mi][ni], 0, 0, 0);
    if (kb + 1 < KB) writeA((kb & 1) ? lA0 : lA1);  // cvt hidden under MFMA latency
  }
  // epilogue: C/D layout col=lane&15, row=(lane>>4)*4+reg
  int cc = c0 + wn;
  if (cc >= NT) return;
  float bv[8] = {0, 0, 0, 0, 0, 0, 0, 0};
  if (B == 0) {
#pragma unroll
    for (int ni = 0; ni < 8; ++ni)
      bv[ni] = bias[s * 640 + cc * 128 + ni * 16 + lm];
  }
#pragma unroll
  for (int mi = 0; mi < 4; ++mi) {
#pragma unroll
    for (int r = 0; r < 4; ++r) {
      int row = wm * 64 + mi * 16 + kq * 4 + r;
      if (m0 + row >= cnt) continue;
      int e = idxb[s * CAP + m0 + row];            // 16-lane broadcast load
      float* po = out + (size_t)e * ROWLEN + XOFF + cc * 128 + lm;
#pragma unroll
      for (int ni = 0; ni < 8; ++ni) po[ni * 16] = acc[mi][ni][r] + bv[ni];
    }
  }
}

__global__ __launch_bounds__(512, 4) void gemm_all(
    const float* __restrict__ x, const char* __restrict__ zeros,
    const unsigned short* __restrict__ Wz,
    const int* __restrict__ counts, const int* __restrict__ idxb,
    const float* __restrict__ bias, float* __restrict__ out) {
  extern __shared__ char sm[];
  // XCD-aware swizzle: all blocks of system s land on XCD (s&7) -> per-system
  // A-slab and W-panel become L2-local. grid = 1280 = 8 xcd * 160.
  int g = blockIdx.x;
  int xcd = g & 7, j = g >> 3;          // j in 0..159
  int s = xcd + 8 * (j / 80);
  int r = j % 80;
  int mt = r / 10, bx = r % 10;         // mt: 8 x 256-row tiles; bx: 3+4+3 col-pairs
  if (bx < 3)      gemm_body<0>(x, zeros, Wz, counts, idxb, bias, out, s, mt, bx,     sm);
  else if (bx < 7) gemm_body<1>(x, zeros, Wz, counts, idxb, bias, out, s, mt, bx - 3, sm);
  else             gemm_body<2>(x, zeros, Wz, counts, idxb, bias, out, s, mt, bx - 7, sm);
}

extern "C" void kernel_launch(void* const* d_in, const int* in_sizes, int n_in,
                              void* d_out, int out_size, void* d_ws, size_t ws_size,
                              hipStream_t stream) {
  const float* x  = (const float*)d_in[0];
  // d_in[1] = x_edge: unused by the reference
  const float* ce = (const float*)d_in[2];
  const int*   eb = (const int*)d_in[3];
  const float* W0 = (const float*)d_in[4];
  const float* b0 = (const float*)d_in[5];
  const float* W1 = (const float*)d_in[6];
  const float* W2 = (const float*)d_in[7];
  float* out = (float*)d_out;
  char* ws = (char*)d_ws;
  int*   counts = (int*)ws;
  char*  zeros  = ws + 256;                      // zeroed by the memset below
  int*   idxb   = (int*)(ws + WS_IDX_OFF);
  float* bias   = (float*)(ws + WS_BIAS_OFF);
  unsigned short* Wz = (unsigned short*)(ws + WS_W_OFF);

  hipMemsetAsync(ws, 0, 1024, stream);           // counts + zeros region
  bucket_kernel<<<48, 256, 0, stream>>>(eb, counts, idxb);
  bias_kernel<<<40, 256, 0, stream>>>(ce, b0, bias);
  mix_all<<<1000, 256, 0, stream>>>(W0, W1, W2, ce, Wz);
  gemm_all<<<1280, 512, 65536, stream>>>(x, zeros, Wz, counts, idxb, bias, out);
}

// Round 3
// 331.972 us; speedup vs baseline: 3.8871x; 3.8871x over previous
//
#include <hip/hip_runtime.h>
#include <cstdint>

#define N_EDGES 12288
#define ROWLEN  2432      // 19*128 floats per edge
#define CAP     2048      // per-system bucket capacity (buckets avg 768)

typedef __bf16 bf16;
typedef __bf16 bf16x8 __attribute__((ext_vector_type(8)));
typedef float  f32x4  __attribute__((ext_vector_type(4)));

#define ELEMS0 (640*640)
#define ELEMS1 (1024*1024)
#define ELEMS2 (768*768)

// ws byte offsets (no xb buffer: A is cast f32->bf16 inside the GEMM)
#define WS_IDX_OFF   1024
#define WS_BIAS_OFF  (WS_IDX_OFF + 16*CAP*4)                 // 132096
#define WS_W_OFF     (WS_BIAS_OFF + 16*640*4)                // 173056
#define WZ_ELEMS     ((size_t)16*(ELEMS0+ELEMS1+ELEMS2))     // 32.77M bf16

// After the SO(2) "hat" fold every branch is a square GEMM with K == N.
template<int B> struct Cfg;
template<> struct Cfg<0> { static constexpr int K=640,  KS=640, XOFF=0,    NT=5;
                           static constexpr size_t WOFF=0; };
template<> struct Cfg<1> { static constexpr int K=1024, KS=512, XOFF=640,  NT=8;
                           static constexpr size_t WOFF=(size_t)16*ELEMS0; };
template<> struct Cfg<2> { static constexpr int K=768,  KS=384, XOFF=1664, NT=6;
                           static constexpr size_t WOFF=(size_t)16*ELEMS0+(size_t)16*ELEMS1; };

__device__ __forceinline__ void async_copy16(const void* g, void* l) {
  // global -> LDS direct copy, 16B/lane; LDS dest = wave-uniform base + lane*16.
  auto gp = reinterpret_cast<const __attribute__((address_space(1))) unsigned int*>(
      reinterpret_cast<uintptr_t>(g));
  auto lp = reinterpret_cast<__attribute__((address_space(3))) unsigned int*>(
      (unsigned int)reinterpret_cast<uintptr_t>(l));
  __builtin_amdgcn_global_load_lds(gp, lp, 16, 0, 0);
}

// ---------------- bucketing: LDS histogram, 16 global atomics per block ------
__global__ void bucket_kernel(const int* __restrict__ eb, int* __restrict__ counts,
                              int* __restrict__ idxb) {
  __shared__ int hcnt[16], hbase[16];
  int tid = threadIdx.x;
  int t = blockIdx.x * 256 + tid;
  if (tid < 16) hcnt[tid] = 0;
  __syncthreads();
  int s = -1, lp = 0;
  if (t < N_EDGES) { s = eb[t]; lp = atomicAdd(&hcnt[s], 1); }
  __syncthreads();
  if (tid < 16) hbase[tid] = atomicAdd(counts + tid, hcnt[tid]);
  __syncthreads();
  if (s >= 0) { int p = hbase[s] + lp; if (p < CAP) idxb[s * CAP + p] = t; }
}

// ---------------- mixed bias ----------------
__global__ void bias_kernel(const float* __restrict__ ce, const float* __restrict__ b0,
                            float* __restrict__ bias) {
  int t = blockIdx.x * 256 + threadIdx.x;   // 0..10239
  int s = t / 640, c = t - s * 640;
  float a = 0.f;
#pragma unroll
  for (int e = 0; e < 8; ++e) a += ce[s * 8 + e] * b0[e * 640 + c];
  bias[t] = a;
}

// ---------------- weight mixing + hat fold + swizzle + bf16 cast ----------------
// dst layout per (branch, system): [kblk][chunk128][kgrp:4][n:128][k8:8] bf16.
template<int B>
__device__ __forceinline__ void mix_body(const float* __restrict__ Wsrc,
                                         const float* ce_s,
                                         unsigned short* __restrict__ Wz, int pos) {
  constexpr int N = Cfg<B>::K, KS = Cfg<B>::KS, NT = N / 128, HALF = N / 2;
  constexpr int SRC_STRIDE = KS * N;
  constexpr size_t DST_STRIDE = (size_t)Cfg<B>::K * N;
  int nn = pos & 127, kgrp = (pos >> 7) & 3, rest = pos >> 9;
  int nt = rest % NT, kblk = rest / NT;
  int i0 = kblk * 32 + kgrp * 8;
  int c  = nt * 128 + nn;
  int si = i0, sc = c; float sg = 1.f;
  if (B > 0 && i0 >= KS) {                      // lower half of hat: [-W2 | W1]
    si = i0 - KS;
    if (c < HALF) { sc = c + HALF; sg = -1.f; } else { sc = c - HALF; }
  }
  float w[8][8];
  const float* p0 = Wsrc + (size_t)si * N + sc;
#pragma unroll
  for (int e = 0; e < 8; ++e) {
    const float* p = p0 + (size_t)e * SRC_STRIDE;
#pragma unroll
    for (int j = 0; j < 8; ++j)
      w[e][j] = sg * __builtin_nontemporal_load(p + (size_t)j * N);  // Wsrc read once
  }
  unsigned short* db = Wz + Cfg<B>::WOFF + (size_t)pos * 8;
#pragma unroll
  for (int s = 0; s < 16; ++s) {
    float a[8] = {0, 0, 0, 0, 0, 0, 0, 0};
#pragma unroll
    for (int e = 0; e < 8; ++e) {
      float cc = ce_s[s * 8 + e];
#pragma unroll
      for (int j = 0; j < 8; ++j) a[j] += cc * w[e][j];
    }
    bf16x8 v;
#pragma unroll
    for (int j = 0; j < 8; ++j) v[j] = (bf16)a[j];
    *(bf16x8*)(db + s * DST_STRIDE) = v;
  }
}

__global__ __launch_bounds__(256) void mix_all(const float* __restrict__ W0,
                                               const float* __restrict__ W1,
                                               const float* __restrict__ W2,
                                               const float* __restrict__ ce,
                                               unsigned short* __restrict__ Wz) {
  __shared__ float ce_s[128];
  int tid = threadIdx.x;
  if (tid < 128) ce_s[tid] = ce[tid];
  __syncthreads();
  int bx = blockIdx.x;
  if (bx < 200)      mix_body<0>(W0, ce_s, Wz, bx * 256 + tid);
  else if (bx < 712) mix_body<1>(W1, ce_s, Wz, (bx - 200) * 256 + tid);
  else               mix_body<2>(W2, ce_s, Wz, (bx - 712) * 256 + tid);
}

// ---------------- grouped GEMM: 128x256 tile, 4 waves (round-0 geometry) -----
// A: f32 global -> reg -> cvt -> bf16 ds_write (T14 split; replaces cast_x pass).
// B: bf16 global_load_lds direct, double-buffered.
// Register budget at __launch_bounds__(256,2): 512/2 = 256 regs/wave.
// acc 128 + sreg 16 + frags 48 + addr ~30 ~= 222 < 256 -> no spill.
// (Round 1 lesson: (512,4) capped at 128 regs/wave -> acc spilled to scratch,
//  2 GB of HBM scratch traffic, 10x slowdown. Never cap below acc size.)
template<int B>
__device__ __forceinline__ void gemm_body(
    const float* __restrict__ x, const char* __restrict__ zeros,
    const unsigned short* __restrict__ Wz,
    const int* __restrict__ counts, const int* __restrict__ idxb,
    const float* __restrict__ bias, float* __restrict__ out,
    int s, int mt, int nt2, char* sm, int* eidx)
{
  constexpr int K = Cfg<B>::K, NT = Cfg<B>::NT, KB = K / 32, XOFF = Cfg<B>::XOFF;
  int cnt = counts[s];
  int m0 = mt * 128;
  if (m0 >= cnt) return;
  int tid = threadIdx.x;
  if (tid < 128) eidx[tid] = (m0 + tid < cnt) ? idxb[s * CAP + m0 + tid] : -1;
  __syncthreads();
  // LDS: A bufs 2x8KB ([kq:4][row:128] 16B chunks), B bufs 2x16KB. Total 48KB.
  char* lA0 = sm;           char* lA1 = sm + 8192;
  char* lB0 = sm + 16384;   char* lB1 = sm + 32768;
  int wv = tid >> 6, ln = tid & 63;
  int wm = wv >> 1, wn = wv & 1;          // 2m x 2n waves, each owns 64x128 output
  int kq = ln >> 4, lm = ln & 15;
  int c0 = nt2 * 2;
  // A source: two threads per row; h selects k-half [h*16, h*16+16) of the 32-k tile
  int r_a = tid >> 1, h = tid & 1;
  const char* arow; int kinc;
  { int e = eidx[r_a];
    if (e >= 0) { arow = (const char*)(x + (size_t)e * ROWLEN + XOFF); kinc = 128; }
    else        { arow = zeros; kinc = 0; } }
  const unsigned short* wb = Wz + Cfg<B>::WOFF + (size_t)s * K * K;

  f32x4 sreg[4];                                   // staged A (16 f32)
  auto loadA = [&](int kb) {                       // issue early (T14 split)
    const char* p = arow + (size_t)kb * kinc + h * 64;
#pragma unroll
    for (int i = 0; i < 4; ++i) sreg[i] = *(const f32x4*)(p + i * 16);
  };
  auto writeA = [&](char* dst) {                   // cvt + ds_write late
#pragma unroll
    for (int c = 0; c < 2; ++c) {
      bf16x8 v;
#pragma unroll
      for (int j = 0; j < 8; ++j) v[j] = (bf16)sreg[c * 2 + (j >> 2)][j & 3];
      *(bf16x8*)(dst + ((2 * h + c) * 128 + r_a) * 16) = v;   // chunk (kq=2h+c, row)
    }
  };
  auto stageB = [&](int kb, char* dst) {
    const unsigned short* base = wb + (size_t)kb * (NT * 4096);
#pragma unroll
    for (int i = 0; i < 4; ++i) {
      int c = i * 256 + tid;                       // 1024 16B chunks per buf
      int ck = c0 + (c >> 9); if (ck > NT - 1) ck = NT - 1;   // clamp (dup, discarded)
      async_copy16(base + (size_t)ck * 4096 + (c & 511) * 8,
                   dst + (i * 256 + wv * 64) * 16);
    }
  };

  f32x4 acc[4][8];
#pragma unroll
  for (int i = 0; i < 4; ++i)
#pragma unroll
    for (int j = 0; j < 8; ++j) {
      acc[i][j][0] = 0.f; acc[i][j][1] = 0.f; acc[i][j][2] = 0.f; acc[i][j][3] = 0.f;
    }

  loadA(0); stageB(0, lB0); writeA(lA0);
#pragma unroll 1
  for (int kb = 0; kb < KB; ++kb) {
    __syncthreads();                              // drains stage(kb) issued last iter
    char* la = (kb & 1) ? lA1 : lA0;
    char* lb = (kb & 1) ? lB1 : lB0;
    if (kb + 1 < KB) {                            // issue next-tile loads first
      loadA(kb + 1);
      stageB(kb + 1, (kb & 1) ? lB0 : lB1);
    }
    bf16x8 af[4], bq[8];
#pragma unroll
    for (int mi = 0; mi < 4; ++mi)
      af[mi] = *(const bf16x8*)(la + kq * 2048 + (wm * 64 + mi * 16 + lm) * 16);
#pragma unroll
    for (int ni = 0; ni < 8; ++ni)
      bq[ni] = *(const bf16x8*)(lb + wn * 8192 + kq * 2048 + (ni * 16 + lm) * 16);
#pragma unroll
    for (int mi = 0; mi < 4; ++mi)
#pragma unroll
      for (int ni = 0; ni < 8; ++ni)
        acc[mi][ni] = __builtin_amdgcn_mfma_f32_16x16x32_bf16(af[mi], bq[ni], acc[mi][ni], 0, 0, 0);
    if (kb + 1 < KB) writeA((kb & 1) ? lA0 : lA1);  // cvt hidden under MFMA phase
  }
  // epilogue: C/D layout col=lane&15, row=(lane>>4)*4+reg
  int cc = c0 + wn;
  if (cc >= NT) return;
  float bv[8] = {0, 0, 0, 0, 0, 0, 0, 0};
  if (B == 0) {
#pragma unroll
    for (int ni = 0; ni < 8; ++ni)
      bv[ni] = bias[s * 640 + cc * 128 + ni * 16 + lm];
  }
#pragma unroll
  for (int mi = 0; mi < 4; ++mi) {
#pragma unroll
    for (int r = 0; r < 4; ++r) {
      int row = wm * 64 + mi * 16 + kq * 4 + r;
      int e = eidx[row];
      if (e < 0) continue;
      float* po = out + (size_t)e * ROWLEN + XOFF + cc * 128 + lm;
#pragma unroll
      for (int ni = 0; ni < 8; ++ni) po[ni * 16] = acc[mi][ni][r] + bv[ni];
    }
  }
}

__global__ __launch_bounds__(256, 2) void gemm_all(
    const float* __restrict__ x, const char* __restrict__ zeros,
    const unsigned short* __restrict__ Wz,
    const int* __restrict__ counts, const int* __restrict__ idxb,
    const float* __restrict__ bias, float* __restrict__ out) {
  extern __shared__ char sm[];
  __shared__ int eidx[128];
  // Bijective XCD swizzle: all 160 blocks of system s land on XCD (s&7) ->
  // W panel (<=4MB/system) and A-slabs stay L2-local across mt re-reads.
  // grid = 2560 = 8 xcd * 320; per XCD: systems (xcd) then (xcd+8), bx fastest.
  int g = blockIdx.x;
  int xcd = g & 7, j = g >> 3;          // j in 0..319
  int s = xcd + 8 * (j / 160);
  int r = j % 160;
  int mt = r / 10, bx = r % 10;         // mt: 16 x 128-row tiles; bx: 3+4+3 col-pairs
  if (bx < 3)      gemm_body<0>(x, zeros, Wz, counts, idxb, bias, out, s, mt, bx,     sm, eidx);
  else if (bx < 7) gemm_body<1>(x, zeros, Wz, counts, idxb, bias, out, s, mt, bx - 3, sm, eidx);
  else             gemm_body<2>(x, zeros, Wz, counts, idxb, bias, out, s, mt, bx - 7, sm, eidx);
}

extern "C" void kernel_launch(void* const* d_in, const int* in_sizes, int n_in,
                              void* d_out, int out_size, void* d_ws, size_t ws_size,
                              hipStream_t stream) {
  const float* x  = (const float*)d_in[0];
  // d_in[1] = x_edge: unused by the reference
  const float* ce = (const float*)d_in[2];
  const int*   eb = (const int*)d_in[3];
  const float* W0 = (const float*)d_in[4];
  const float* b0 = (const float*)d_in[5];
  const float* W1 = (const float*)d_in[6];
  const float* W2 = (const float*)d_in[7];
  float* out = (float*)d_out;
  char* ws = (char*)d_ws;
  int*   counts = (int*)ws;
  char*  zeros  = ws + 256;                      // zeroed by the memset below
  int*   idxb   = (int*)(ws + WS_IDX_OFF);
  float* bias   = (float*)(ws + WS_BIAS_OFF);
  unsigned short* Wz = (unsigned short*)(ws + WS_W_OFF);

  hipMemsetAsync(ws, 0, 1024, stream);           // counts + zeros region
  bucket_kernel<<<48, 256, 0, stream>>>(eb, counts, idxb);
  bias_kernel<<<40, 256, 0, stream>>>(ce, b0, bias);
  mix_all<<<1000, 256, 0, stream>>>(W0, W1, W2, ce, Wz);
  gemm_all<<<2560, 256, 49152, stream>>>(x, zeros, Wz, counts, idxb, bias, out);
}

// Round 4
// 328.588 us; speedup vs baseline: 3.9271x; 1.0103x over previous
//
#include <hip/hip_runtime.h>
#include <cstdint>

#define N_EDGES 12288
#define ROWLEN  2432      // 19*128 floats per edge
#define CAP     2048      // per-system bucket capacity (buckets avg 768)

typedef __bf16 bf16;
typedef __bf16 bf16x8 __attribute__((ext_vector_type(8)));
typedef float  f32x4  __attribute__((ext_vector_type(4)));

#define ELEMS0 (640*640)
#define ELEMS1 (1024*1024)
#define ELEMS2 (768*768)

// ws byte offsets (no xb buffer: A is cast f32->bf16 inside the GEMM)
#define WS_IDX_OFF   1024
#define WS_BIAS_OFF  (WS_IDX_OFF + 16*CAP*4)                 // 132096
#define WS_W_OFF     (WS_BIAS_OFF + 16*640*4)                // 173056
#define WZ_ELEMS     ((size_t)16*(ELEMS0+ELEMS1+ELEMS2))     // 32.77M bf16

// After the SO(2) "hat" fold every branch is a square GEMM with K == N.
template<int B> struct Cfg;
template<> struct Cfg<0> { static constexpr int K=640,  KS=640, XOFF=0,    NT=5;
                           static constexpr size_t WOFF=0; };
template<> struct Cfg<1> { static constexpr int K=1024, KS=512, XOFF=640,  NT=8;
                           static constexpr size_t WOFF=(size_t)16*ELEMS0; };
template<> struct Cfg<2> { static constexpr int K=768,  KS=384, XOFF=1664, NT=6;
                           static constexpr size_t WOFF=(size_t)16*ELEMS0+(size_t)16*ELEMS1; };

__device__ __forceinline__ void async_copy16(const void* g, void* l) {
  // global -> LDS direct copy, 16B/lane; LDS dest = wave-uniform base + lane*16.
  auto gp = reinterpret_cast<const __attribute__((address_space(1))) unsigned int*>(
      reinterpret_cast<uintptr_t>(g));
  auto lp = reinterpret_cast<__attribute__((address_space(3))) unsigned int*>(
      (unsigned int)reinterpret_cast<uintptr_t>(l));
  __builtin_amdgcn_global_load_lds(gp, lp, 16, 0, 0);
}

// ---------------- bucketing: LDS histogram, 16 global atomics per block ------
__global__ void bucket_kernel(const int* __restrict__ eb, int* __restrict__ counts,
                              int* __restrict__ idxb) {
  __shared__ int hcnt[16], hbase[16];
  int tid = threadIdx.x;
  int t = blockIdx.x * 256 + tid;
  if (tid < 16) hcnt[tid] = 0;
  __syncthreads();
  int s = -1, lp = 0;
  if (t < N_EDGES) { s = eb[t]; lp = atomicAdd(&hcnt[s], 1); }
  __syncthreads();
  if (tid < 16) hbase[tid] = atomicAdd(counts + tid, hcnt[tid]);
  __syncthreads();
  if (s >= 0) { int p = hbase[s] + lp; if (p < CAP) idxb[s * CAP + p] = t; }
}

// ---------------- mixed bias ----------------
__global__ void bias_kernel(const float* __restrict__ ce, const float* __restrict__ b0,
                            float* __restrict__ bias) {
  int t = blockIdx.x * 256 + threadIdx.x;   // 0..10239
  int s = t / 640, c = t - s * 640;
  float a = 0.f;
#pragma unroll
  for (int e = 0; e < 8; ++e) a += ce[s * 8 + e] * b0[e * 640 + c];
  bias[t] = a;
}

// ---------------- weight mixing + hat fold + swizzle + bf16 cast ----------------
// dst layout per (branch, system): [kblk][chunk128][kgrp:4][n:128][k8:8] bf16.
template<int B>
__device__ __forceinline__ void mix_body(const float* __restrict__ Wsrc,
                                         const float* ce_s,
                                         unsigned short* __restrict__ Wz, int pos) {
  constexpr int N = Cfg<B>::K, KS = Cfg<B>::KS, NT = N / 128, HALF = N / 2;
  constexpr int SRC_STRIDE = KS * N;
  constexpr size_t DST_STRIDE = (size_t)Cfg<B>::K * N;
  int nn = pos & 127, kgrp = (pos >> 7) & 3, rest = pos >> 9;
  int nt = rest % NT, kblk = rest / NT;
  int i0 = kblk * 32 + kgrp * 8;
  int c  = nt * 128 + nn;
  int si = i0, sc = c; float sg = 1.f;
  if (B > 0 && i0 >= KS) {                      // lower half of hat: [-W2 | W1]
    si = i0 - KS;
    if (c < HALF) { sc = c + HALF; sg = -1.f; } else { sc = c - HALF; }
  }
  float w[8][8];
  const float* p0 = Wsrc + (size_t)si * N + sc;
#pragma unroll
  for (int e = 0; e < 8; ++e) {
    const float* p = p0 + (size_t)e * SRC_STRIDE;
#pragma unroll
    for (int j = 0; j < 8; ++j)
      w[e][j] = sg * __builtin_nontemporal_load(p + (size_t)j * N);  // Wsrc read once
  }
  unsigned short* db = Wz + Cfg<B>::WOFF + (size_t)pos * 8;
#pragma unroll
  for (int s = 0; s < 16; ++s) {
    float a[8] = {0, 0, 0, 0, 0, 0, 0, 0};
#pragma unroll
    for (int e = 0; e < 8; ++e) {
      float cc = ce_s[s * 8 + e];
#pragma unroll
      for (int j = 0; j < 8; ++j) a[j] += cc * w[e][j];
    }
    bf16x8 v;
#pragma unroll
    for (int j = 0; j < 8; ++j) v[j] = (bf16)a[j];
    *(bf16x8*)(db + s * DST_STRIDE) = v;
  }
}

__global__ __launch_bounds__(256) void mix_all(const float* __restrict__ W0,
                                               const float* __restrict__ W1,
                                               const float* __restrict__ W2,
                                               const float* __restrict__ ce,
                                               unsigned short* __restrict__ Wz) {
  __shared__ float ce_s[128];
  int tid = threadIdx.x;
  if (tid < 128) ce_s[tid] = ce[tid];
  __syncthreads();
  int bx = blockIdx.x;
  if (bx < 200)      mix_body<0>(W0, ce_s, Wz, bx * 256 + tid);
  else if (bx < 712) mix_body<1>(W1, ce_s, Wz, (bx - 200) * 256 + tid);
  else               mix_body<2>(W2, ce_s, Wz, (bx - 712) * 256 + tid);
}

// ---------------- grouped GEMM: 128x256 tile, 4 waves, counted-vmcnt pipeline -
// Schedule (T3+T4): B triple-buffered, staged 2 iters ahead via global_load_lds;
// A double-buffered via f32 global->reg->cvt->ds_write (reg A(kb+1) in sreg).
// The counted waits are compiler-generated: writeA's use of sreg (=loadA(kb+1),
// issued AFTER stageB(kb+1)) forces vmcnt that retires exactly B(kb+1). In-loop
// we never drain vmcnt(0); 8 VMEM ops stay in flight across every barrier.
// Raw s_barrier + own-lgkmcnt(0) + sched_barrier(0) (rule 18) replace
// __syncthreads (which would emit vmcnt(0) and expose a full LLC round-trip
// per K-step - the measured 82% stall of round 3).
template<int B>
__device__ __forceinline__ void gemm_body(
    const float* __restrict__ x, const char* __restrict__ zeros,
    const unsigned short* __restrict__ Wz,
    const int* __restrict__ counts, const int* __restrict__ idxb,
    const float* __restrict__ bias, float* __restrict__ out,
    int s, int mt, int nt2, char* sm, int* eidx)
{
  constexpr int K = Cfg<B>::K, NT = Cfg<B>::NT, KB = K / 32, XOFF = Cfg<B>::XOFF;
  int cnt = counts[s];
  int m0 = mt * 128;
  if (m0 >= cnt) return;
  int tid = threadIdx.x;
  if (tid < 128) eidx[tid] = (m0 + tid < cnt) ? idxb[s * CAP + m0 + tid] : -1;
  __syncthreads();
  // LDS: A bufs 2x8KB ([kq:4][row:128] 16B chunks), B bufs 3x16KB. Total 64KB.
  char* Acur = sm;          char* Anxt = sm + 8192;
  char* Bc = sm + 16384;    char* Bm = sm + 32768;    char* Bn = sm + 49152;
  int wv = tid >> 6, ln = tid & 63;
  int wm = wv >> 1, wn = wv & 1;          // 2m x 2n waves, each owns 64x128 output
  int kq = ln >> 4, lm = ln & 15;
  int c0 = nt2 * 2;
  // A source: two threads per row; h selects k-half [h*16, h*16+16) of the 32-k tile
  int r_a = tid >> 1, h = tid & 1;
  const char* arow; int kinc;
  { int e = eidx[r_a];
    if (e >= 0) { arow = (const char*)(x + (size_t)e * ROWLEN + XOFF); kinc = 128; }
    else        { arow = zeros; kinc = 0; } }
  const unsigned short* wb = Wz + Cfg<B>::WOFF + (size_t)s * K * K;

  f32x4 sreg[4];                                   // staged A (16 f32)
  auto loadA = [&](int kb) {                       // issue early (T14 split)
    const char* p = arow + (size_t)kb * kinc + h * 64;
#pragma unroll
    for (int i = 0; i < 4; ++i) sreg[i] = *(const f32x4*)(p + i * 16);
  };
  auto writeA = [&](char* dst) {                   // cvt + ds_write late
#pragma unroll
    for (int c = 0; c < 2; ++c) {
      bf16x8 v;
#pragma unroll
      for (int j = 0; j < 8; ++j) v[j] = (bf16)sreg[c * 2 + (j >> 2)][j & 3];
      *(bf16x8*)(dst + ((2 * h + c) * 128 + r_a) * 16) = v;   // chunk (kq=2h+c, row)
    }
  };
  auto stageB = [&](int kb, char* dst) {
    const unsigned short* base = wb + (size_t)kb * (NT * 4096);
#pragma unroll
    for (int i = 0; i < 4; ++i) {
      int c = i * 256 + tid;                       // 1024 16B chunks per buf
      int ck = c0 + (c >> 9); if (ck > NT - 1) ck = NT - 1;   // clamp (dup, discarded)
      async_copy16(base + (size_t)ck * 4096 + (c & 511) * 8,
                   dst + (i * 256 + wv * 64) * 16);
    }
  };

  f32x4 acc[4][8];
#pragma unroll
  for (int i = 0; i < 4; ++i)
#pragma unroll
    for (int j = 0; j < 8; ++j) {
      acc[i][j][0] = 0.f; acc[i][j][1] = 0.f; acc[i][j][2] = 0.f; acc[i][j][3] = 0.f;
    }

  // Prologue: establish invariant for iter 0:
  //   Acur = A(0) (ds-written), Bc = B(0) (landed),
  //   Bm = B(1) in flight (4), sreg = A(1) in flight (4).
  loadA(0);                    // 4 vmem (issued first -> retired by writeA's wait)
  stageB(0, Bc);               // 4 global_load_lds
  writeA(Acur);                // compiler waits vmcnt(4) for sreg, then ds_writes
  asm volatile("s_waitcnt vmcnt(0)" ::: "memory");   // B(0) landed (one-time drain)
  stageB(1, Bm);
  loadA(1);
  asm volatile("s_waitcnt lgkmcnt(0)" ::: "memory"); // own A(0) ds_writes done
  __builtin_amdgcn_s_barrier();
  __builtin_amdgcn_sched_barrier(0);

#pragma unroll 1
  for (int kb = 0; kb < KB; ++kb) {
    if (kb + 2 < KB) stageB(kb + 2, Bn);          // prefetch depth-2 (4 gl_lds)
    bf16x8 af[4], bq[8];
#pragma unroll
    for (int mi = 0; mi < 4; ++mi)
      af[mi] = *(const bf16x8*)(Acur + kq * 2048 + (wm * 64 + mi * 16 + lm) * 16);
#pragma unroll
    for (int ni = 0; ni < 8; ++ni)
      bq[ni] = *(const bf16x8*)(Bc + wn * 8192 + kq * 2048 + (ni * 16 + lm) * 16);
    __builtin_amdgcn_s_setprio(1);
#pragma unroll
    for (int mi = 0; mi < 4; ++mi)
#pragma unroll
      for (int ni = 0; ni < 8; ++ni)
        acc[mi][ni] = __builtin_amdgcn_mfma_f32_16x16x32_bf16(af[mi], bq[ni], acc[mi][ni], 0, 0, 0);
    __builtin_amdgcn_s_setprio(0);
    if (kb + 1 < KB) {
      writeA(Anxt);            // auto vmcnt wait retires loadA(kb+1) AND B(kb+1)
      if (kb + 2 < KB) loadA(kb + 2);             // refill sreg for next writeA
    }
    asm volatile("s_waitcnt lgkmcnt(0)" ::: "memory");  // own ds_writes visible
    __builtin_amdgcn_s_barrier();                 // raw: vmcnt stays nonzero
    __builtin_amdgcn_sched_barrier(0);
    char* t = Acur; Acur = Anxt; Anxt = t;        // rotate buffers
    char* tb = Bc; Bc = Bm; Bm = Bn; Bn = tb;
  }
  // epilogue: C/D layout col=lane&15, row=(lane>>4)*4+reg
  int cc = c0 + wn;
  if (cc >= NT) return;
  float bv[8] = {0, 0, 0, 0, 0, 0, 0, 0};
  if (B == 0) {
#pragma unroll
    for (int ni = 0; ni < 8; ++ni)
      bv[ni] = bias[s * 640 + cc * 128 + ni * 16 + lm];
  }
#pragma unroll
  for (int mi = 0; mi < 4; ++mi) {
#pragma unroll
    for (int r = 0; r < 4; ++r) {
      int row = wm * 64 + mi * 16 + kq * 4 + r;
      int e = eidx[row];
      if (e < 0) continue;
      float* po = out + (size_t)e * ROWLEN + XOFF + cc * 128 + lm;
#pragma unroll
      for (int ni = 0; ni < 8; ++ni) po[ni * 16] = acc[mi][ni][r] + bv[ni];
    }
  }
}

__global__ __launch_bounds__(256, 2) void gemm_all(
    const float* __restrict__ x, const char* __restrict__ zeros,
    const unsigned short* __restrict__ Wz,
    const int* __restrict__ counts, const int* __restrict__ idxb,
    const float* __restrict__ bias, float* __restrict__ out) {
  extern __shared__ char sm[];
  __shared__ int eidx[128];
  // Bijective XCD swizzle: all 160 blocks of system s land on XCD (s&7) ->
  // W panel (<=4MB/system) and A-slabs stay L2-local across mt re-reads.
  // grid = 2560 = 8 xcd * 320; per XCD: systems (xcd) then (xcd+8), bx fastest.
  int g = blockIdx.x;
  int xcd = g & 7, j = g >> 3;          // j in 0..319
  int s = xcd + 8 * (j / 160);
  int r = j % 160;
  int mt = r / 10, bx = r % 10;         // mt: 16 x 128-row tiles; bx: 3+4+3 col-pairs
  if (bx < 3)      gemm_body<0>(x, zeros, Wz, counts, idxb, bias, out, s, mt, bx,     sm, eidx);
  else if (bx < 7) gemm_body<1>(x, zeros, Wz, counts, idxb, bias, out, s, mt, bx - 3, sm, eidx);
  else             gemm_body<2>(x, zeros, Wz, counts, idxb, bias, out, s, mt, bx - 7, sm, eidx);
}

extern "C" void kernel_launch(void* const* d_in, const int* in_sizes, int n_in,
                              void* d_out, int out_size, void* d_ws, size_t ws_size,
                              hipStream_t stream) {
  const float* x  = (const float*)d_in[0];
  // d_in[1] = x_edge: unused by the reference
  const float* ce = (const float*)d_in[2];
  const int*   eb = (const int*)d_in[3];
  const float* W0 = (const float*)d_in[4];
  const float* b0 = (const float*)d_in[5];
  const float* W1 = (const float*)d_in[6];
  const float* W2 = (const float*)d_in[7];
  float* out = (float*)d_out;
  char* ws = (char*)d_ws;
  int*   counts = (int*)ws;
  char*  zeros  = ws + 256;                      // zeroed by the memset below
  int*   idxb   = (int*)(ws + WS_IDX_OFF);
  float* bias   = (float*)(ws + WS_BIAS_OFF);
  unsigned short* Wz = (unsigned short*)(ws + WS_W_OFF);

  hipMemsetAsync(ws, 0, 1024, stream);           // counts + zeros region
  bucket_kernel<<<48, 256, 0, stream>>>(eb, counts, idxb);
  bias_kernel<<<40, 256, 0, stream>>>(ce, b0, bias);
  mix_all<<<1000, 256, 0, stream>>>(W0, W1, W2, ce, Wz);
  gemm_all<<<2560, 256, 65536, stream>>>(x, zeros, Wz, counts, idxb, bias, out);
}